// Round 14
// baseline (1345.342 us; speedup 1.0000x reference)
//
#include <hip/hip_runtime.h>
#include <cstdint>
#include <cstddef>
#include <type_traits>

// Problem constants
#define B_ 8
#define V_ 16
#define T_ 64
#define E_ 240          // V*(V-1)
#define H_ 256
#define RH_ 64
#define K_ 2
#define DIN_ 6
#define BET_ (B_*E_*T_)   // 122880
#define BVT_ (B_*V_*T_)   // 8192
#define BE_ (B_*E_)       // 1920

typedef unsigned short ushort_t;
typedef unsigned int u32;
typedef __attribute__((ext_vector_type(8))) short bf16x8;
typedef __attribute__((ext_vector_type(4))) float f32x4;

__device__ __forceinline__ float eluf(float x) { return x > 0.f ? x : __expf(x) - 1.f; }
__device__ __forceinline__ float fsig(float x) { return 1.f / (1.f + __expf(-x)); }
__device__ __forceinline__ float ftanh_(float x) {
    float y = fminf(fmaxf(x, -8.f), 8.f);
    float e = __expf(2.f * y);
    return (e - 1.f) / (e + 1.f);
}
__device__ __forceinline__ float b2f(ushort_t u) {
    union { float f; uint32_t i; } v; v.i = ((uint32_t)u) << 16; return v.f;
}
__device__ __forceinline__ ushort_t f2b(float f) {
    union { float f; uint32_t i; } v; v.f = f;
    uint32_t r = (v.i + 0x7FFFu + ((v.i >> 16) & 1u)) >> 16;
    return (ushort_t)r;
}

// async global->LDS, 16B per lane; LDS dest = wave-uniform base + lane*16
__device__ __forceinline__ void gll16(const void* g, void* l) {
    __builtin_amdgcn_global_load_lds(
        (const __attribute__((address_space(1))) u32*)g,
        (__attribute__((address_space(3))) u32*)l, 16, 0, 0);
}

// ===========================================================================
// 16-wave BM=512 MFMA GEMM: C = act(A@W.T + b1 (+b2)), bf16 out, N=256.
// Grid = M/512 = 240 blocks -> single fully-resident round on 256 CUs.
// Wave w (0..15): wm=w>>2, wn=w&3; wave-tile 128x64 via mh-split (proven).
// LDS 3 slots x 48 entries x 1KB = 144 KB; entries 0..31 = A frags,
// 32..47 = B frags. 3 loads/wave/half; counted vmcnt(3), 0 at tail
// (mlp3-proven 3-slot pattern: stage h+2, wait newest-3).
// In-place safe for per-block rows (A loads drained before epilogue stores).
// ===========================================================================
template<int KD, int ACT>
__global__ __launch_bounds__(1024, 4) void gemm16_k(
    const ushort_t* __restrict__ A, const ushort_t* __restrict__ Wt,
    const float* __restrict__ b1, const float* __restrict__ b2,
    ushort_t* __restrict__ C)
{
    __shared__ ushort_t lds[3][48][512];   // 144 KB
    const int tid = threadIdx.x;
    const int lane = tid & 63;
    const int w = tid >> 6;                // 0..15
    const int wm = w >> 2, wn = w & 3;     // 4m x 4n
    const int m0 = blockIdx.x * 512;
    const int r16 = lane & 15, kq = lane >> 4;
    constexpr int NH = KD / 32;

    const ushort_t* Ag0 = A + (size_t)(m0 + w * 16 + r16) * KD + kq * 8;
    const ushort_t* Ag1 = A + (size_t)(m0 + (w + 16) * 16 + r16) * KD + kq * 8;
    const ushort_t* Bg  = Wt + (size_t)(w * 16 + r16) * KD + kq * 8;

    f32x4 acc[8][4];
    #pragma unroll
    for (int i = 0; i < 8; ++i)
        #pragma unroll
        for (int j = 0; j < 4; ++j)
            acc[i][j] = (f32x4){0.f, 0.f, 0.f, 0.f};

#define ST16(h) do { int sl_ = (h) % 3; int kk_ = (h) * 32;                 \
    gll16(Ag0 + kk_, &lds[sl_][w][0]);                                      \
    gll16(Ag1 + kk_, &lds[sl_][w + 16][0]);                                 \
    gll16(Bg + kk_, &lds[sl_][32 + w][0]);                                  \
} while (0)

    ST16(0); ST16(1);
    asm volatile("s_waitcnt vmcnt(3)" ::: "memory");   // half 0 landed
    __builtin_amdgcn_s_barrier();

    for (int h = 0; h < NH; ++h) {
        if (h + 2 < NH) ST16(h + 2);
        const int sl = h % 3;
        bf16x8 bfr[4];
        #pragma unroll
        for (int nf = 0; nf < 4; ++nf)
            bfr[nf] = *(const bf16x8*)&lds[sl][32 + wn * 4 + nf][lane * 8];
        #pragma unroll
        for (int mh = 0; mh < 2; ++mh) {
            bf16x8 af[4];
            #pragma unroll
            for (int mf = 0; mf < 4; ++mf)
                af[mf] = *(const bf16x8*)&lds[sl][wm * 8 + mh * 4 + mf][lane * 8];
            __builtin_amdgcn_s_setprio(1);
            #pragma unroll
            for (int mf = 0; mf < 4; ++mf)
                #pragma unroll
                for (int nf = 0; nf < 4; ++nf)
                    acc[mh * 4 + mf][nf] = __builtin_amdgcn_mfma_f32_16x16x32_bf16(
                        bfr[nf], af[mf], acc[mh * 4 + mf][nf], 0, 0, 0);
            __builtin_amdgcn_s_setprio(0);
        }
        asm volatile("s_waitcnt lgkmcnt(0)" ::: "memory");
        if (h <= NH - 3)      { asm volatile("s_waitcnt vmcnt(3)" ::: "memory"); }
        else if (h == NH - 2) { asm volatile("s_waitcnt vmcnt(0)" ::: "memory"); }
        if (h < NH - 1) __builtin_amdgcn_s_barrier();
    }
#undef ST16

    #pragma unroll
    for (int mi = 0; mi < 8; ++mi) {
        int mrow = m0 + wm * 128 + mi * 16 + r16;
        #pragma unroll
        for (int nf = 0; nf < 4; ++nf) {
            int nb = wn * 64 + nf * 16 + kq * 4;
            float4 bb = *(const float4*)&b1[nb];
            if (b2) {
                float4 b2v = *(const float4*)&b2[nb];
                bb.x += b2v.x; bb.y += b2v.y; bb.z += b2v.z; bb.w += b2v.w;
            }
            float v0 = acc[mi][nf][0] + bb.x;
            float v1 = acc[mi][nf][1] + bb.y;
            float v2 = acc[mi][nf][2] + bb.z;
            float v3 = acc[mi][nf][3] + bb.w;
            if (ACT) { v0 = eluf(v0); v1 = eluf(v1); v2 = eluf(v2); v3 = eluf(v3); }
            ushort4 o; o.x = f2b(v0); o.y = f2b(v1); o.z = f2b(v2); o.w = f2b(v3);
            *(ushort4*)&C[(size_t)mrow * 256 + nb] = o;
        }
    }
}

// ===========================================================================
// 16-wave BM=512 mlp4 layer-1: KD=768, A gathered on the fly.
// Same schedule as gemm16_k; A frags w and w+16 come from SEND/RECV/EA
// segments (whole 32-col halves lie in one segment).
// ===========================================================================
__global__ __launch_bounds__(1024, 4) void gemm16_mlp4_k(
    const ushort_t* __restrict__ X2b, const ushort_t* __restrict__ EA,
    const ushort_t* __restrict__ Wt, const float* __restrict__ b1,
    ushort_t* __restrict__ C)
{
    __shared__ ushort_t lds[3][48][512];   // 144 KB
    const int tid = threadIdx.x;
    const int lane = tid & 63;
    const int w = tid >> 6;
    const int wm = w >> 2, wn = w & 3;
    const int m0 = blockIdx.x * 512;
    const int r16 = lane & 15, kq = lane >> 4;
    constexpr int NH = 24;

    const ushort_t* AS[2]; const ushort_t* AR[2]; const ushort_t* AE[2];
    #pragma unroll
    for (int ff = 0; ff < 2; ++ff) {
        int f = w + ff * 16;
        int m = m0 + f * 16 + r16;
        int be = m >> 6, t = m & 63;
        int b = be / E_, e = be % E_;
        int s = e / (V_ - 1);
        int r0 = e % (V_ - 1);
        int rr = r0 + (r0 >= s ? 1 : 0);
        AS[ff] = X2b + ((size_t)((b * V_ + s) * T_ + t)) * H_ + kq * 8;
        AR[ff] = X2b + ((size_t)((b * V_ + rr) * T_ + t)) * H_ + kq * 8;
        AE[ff] = EA + (size_t)m * H_ + kq * 8;
    }
    const ushort_t* Bg = Wt + (size_t)(w * 16 + r16) * 768 + kq * 8;

    f32x4 acc[8][4];
    #pragma unroll
    for (int i = 0; i < 8; ++i)
        #pragma unroll
        for (int j = 0; j < 4; ++j)
            acc[i][j] = (f32x4){0.f, 0.f, 0.f, 0.f};

#define STM16(h) do { int sl_ = (h) % 3; int kk_ = (h) * 32;                \
    int seg_ = kk_ >> 8, off_ = kk_ & 255;                                  \
    const ushort_t* a0_ = (seg_ == 0 ? AS[0] : seg_ == 1 ? AR[0] : AE[0]) + off_; \
    const ushort_t* a1_ = (seg_ == 0 ? AS[1] : seg_ == 1 ? AR[1] : AE[1]) + off_; \
    gll16(a0_, &lds[sl_][w][0]);                                            \
    gll16(a1_, &lds[sl_][w + 16][0]);                                       \
    gll16(Bg + kk_, &lds[sl_][32 + w][0]);                                  \
} while (0)

    STM16(0); STM16(1);
    asm volatile("s_waitcnt vmcnt(3)" ::: "memory");
    __builtin_amdgcn_s_barrier();

    for (int h = 0; h < NH; ++h) {
        if (h + 2 < NH) STM16(h + 2);
        const int sl = h % 3;
        bf16x8 bfr[4];
        #pragma unroll
        for (int nf = 0; nf < 4; ++nf)
            bfr[nf] = *(const bf16x8*)&lds[sl][32 + wn * 4 + nf][lane * 8];
        #pragma unroll
        for (int mh = 0; mh < 2; ++mh) {
            bf16x8 af[4];
            #pragma unroll
            for (int mf = 0; mf < 4; ++mf)
                af[mf] = *(const bf16x8*)&lds[sl][wm * 8 + mh * 4 + mf][lane * 8];
            __builtin_amdgcn_s_setprio(1);
            #pragma unroll
            for (int mf = 0; mf < 4; ++mf)
                #pragma unroll
                for (int nf = 0; nf < 4; ++nf)
                    acc[mh * 4 + mf][nf] = __builtin_amdgcn_mfma_f32_16x16x32_bf16(
                        bfr[nf], af[mf], acc[mh * 4 + mf][nf], 0, 0, 0);
            __builtin_amdgcn_s_setprio(0);
        }
        asm volatile("s_waitcnt lgkmcnt(0)" ::: "memory");
        if (h <= NH - 3)      { asm volatile("s_waitcnt vmcnt(3)" ::: "memory"); }
        else if (h == NH - 2) { asm volatile("s_waitcnt vmcnt(0)" ::: "memory"); }
        if (h < NH - 1) __builtin_amdgcn_s_barrier();
    }
#undef STM16

    #pragma unroll
    for (int mi = 0; mi < 8; ++mi) {
        int mrow = m0 + wm * 128 + mi * 16 + r16;
        #pragma unroll
        for (int nf = 0; nf < 4; ++nf) {
            int nb = wn * 64 + nf * 16 + kq * 4;
            float4 bb = *(const float4*)&b1[nb];
            float v0 = eluf(acc[mi][nf][0] + bb.x);
            float v1 = eluf(acc[mi][nf][1] + bb.y);
            float v2 = eluf(acc[mi][nf][2] + bb.z);
            float v3 = eluf(acc[mi][nf][3] + bb.w);
            ushort4 o; o.x = f2b(v0); o.y = f2b(v1); o.z = f2b(v2); o.w = f2b(v3);
            *(ushort4*)&C[(size_t)mrow * 256 + nb] = o;
        }
    }
}

// ===========================================================================
// VALU ein GEMM (r2-proven): H1 = elu(concat(ear,epos)@ef_w1.T + b1), Kd=16.
// ===========================================================================
__global__ __launch_bounds__(256) void gemm_ein_k(
    const float* __restrict__ ear, const float* __restrict__ epos,
    const float* __restrict__ W, const float* __restrict__ b1,
    ushort_t* __restrict__ C)
{
    __shared__ float As[16][64];
    __shared__ float Ws[16][64];
    const int m0 = blockIdx.x * 64, n0 = blockIdx.y * 64;
    const int tid = threadIdx.x;
    const int tm = tid >> 4, tn = tid & 15;
    const int lm = tid >> 2, lq = tid & 3;
    const int m = m0 + lm;
    float a_[4];
    #pragma unroll
    for (int q = 0; q < 4; ++q) {
        int c = lq * 4 + q;
        a_[q] = (c < 13) ? ear[(size_t)m * 13 + c] : epos[(size_t)m * 3 + (c - 13)];
    }
    float4 wv = *(const float4*)(W + (size_t)(n0 + lm) * 16 + lq * 4);
    As[lq*4+0][lm] = a_[0]; As[lq*4+1][lm] = a_[1]; As[lq*4+2][lm] = a_[2]; As[lq*4+3][lm] = a_[3];
    Ws[lq*4+0][lm] = wv.x; Ws[lq*4+1][lm] = wv.y; Ws[lq*4+2][lm] = wv.z; Ws[lq*4+3][lm] = wv.w;
    __syncthreads();
    float acc[4][4] = {};
    #pragma unroll
    for (int k = 0; k < 16; ++k) {
        float4 a = *(const float4*)&As[k][tm * 4];
        float4 w = *(const float4*)&Ws[k][tn * 4];
        float aa[4] = {a.x, a.y, a.z, a.w};
        float ww[4] = {w.x, w.y, w.z, w.w};
        #pragma unroll
        for (int i = 0; i < 4; ++i)
            #pragma unroll
            for (int j = 0; j < 4; ++j)
                acc[i][j] += aa[i] * ww[j];
    }
    #pragma unroll
    for (int i = 0; i < 4; ++i) {
        ushort4 o;
        o.x = f2b(eluf(acc[i][0] + b1[n0 + tn*4 + 0]));
        o.y = f2b(eluf(acc[i][1] + b1[n0 + tn*4 + 1]));
        o.z = f2b(eluf(acc[i][2] + b1[n0 + tn*4 + 2]));
        o.w = f2b(eluf(acc[i][3] + b1[n0 + tn*4 + 3]));
        *(ushort4*)(C + (size_t)(m0 + tm * 4 + i) * H_ + (n0 + tn * 4)) = o;
    }
}

// ===========================================================================
// FUSED mlp3 (both layers, node rows) — unchanged from r10 (works)
// ===========================================================================
__global__ __launch_bounds__(512, 1) void gemm8_mlp3_k(
    const ushort_t* __restrict__ Xb, const ushort_t* __restrict__ w1,
    const float* __restrict__ b1, const ushort_t* __restrict__ w2,
    const float* __restrict__ b2, ushort_t* __restrict__ Out)
{
    __shared__ ushort_t H1[8][8][512];   // 64 KB
    __shared__ ushort_t slots[36864];    // 72 KB
    const int tid = threadIdx.x;
    const int lane = tid & 63;
    const int w = tid >> 6;
    const int m0 = blockIdx.x * 128;
    const int r16 = lane & 15, kq = lane >> 4;

    const ushort_t* Ag = Xb + (size_t)(m0 + w * 16 + r16) * 256 + kq * 8;
    const size_t bo0 = (size_t)(2 * w * 16 + r16) * 256 + kq * 8;
    const size_t bo1 = (size_t)((2 * w + 1) * 16 + r16) * 256 + kq * 8;

    float4 bb1[2], bb2[2];
    #pragma unroll
    for (int nf = 0; nf < 2; ++nf) {
        bb1[nf] = *(const float4*)&b1[w * 32 + nf * 16 + kq * 4];
        bb2[nf] = *(const float4*)&b2[w * 32 + nf * 16 + kq * 4];
    }

#define M3_ST0(h) do { int sl_ = (h) % 3;                                   \
    gll16(Ag + (h) * 32, &slots[sl_ * 12288 + w * 512]);                    \
    gll16(w1 + bo0 + (h) * 32, &slots[sl_ * 12288 + 4096 + 2 * w * 512]);   \
    gll16(w1 + bo1 + (h) * 32, &slots[sl_ * 12288 + 4096 + (2 * w + 1) * 512]); \
} while (0)
#define M3_ST1(h) do { int sl_ = (h) & 1; int kk_ = (h) * 32;               \
    gll16(w2 + bo0 + kk_, &slots[sl_ * 8192 + 2 * w * 512]);                \
    gll16(w2 + bo1 + kk_, &slots[sl_ * 8192 + (2 * w + 1) * 512]);          \
} while (0)

    f32x4 acc0[8][2];
    #pragma unroll
    for (int i = 0; i < 8; ++i) { acc0[i][0] = (f32x4){0,0,0,0}; acc0[i][1] = (f32x4){0,0,0,0}; }

    M3_ST0(0); M3_ST0(1);
    asm volatile("s_waitcnt vmcnt(3)" ::: "memory");
    __builtin_amdgcn_s_barrier();

    for (int h = 0; h < 8; ++h) {
        if (h + 2 < 8) M3_ST0(h + 2);
        const int sl = h % 3;
        bf16x8 af[8], bfr[2];
        #pragma unroll
        for (int mf = 0; mf < 8; ++mf)
            af[mf] = *(const bf16x8*)&slots[sl * 12288 + mf * 512 + lane * 8];
        #pragma unroll
        for (int nf = 0; nf < 2; ++nf)
            bfr[nf] = *(const bf16x8*)&slots[sl * 12288 + 4096 + (2 * w + nf) * 512 + lane * 8];
        #pragma unroll
        for (int mf = 0; mf < 8; ++mf)
            #pragma unroll
            for (int nf = 0; nf < 2; ++nf)
                acc0[mf][nf] = __builtin_amdgcn_mfma_f32_16x16x32_bf16(bfr[nf], af[mf], acc0[mf][nf], 0, 0, 0);
        asm volatile("s_waitcnt lgkmcnt(0)" ::: "memory");
        if (h <= 5)      { asm volatile("s_waitcnt vmcnt(3)" ::: "memory"); }
        else if (h == 6) { asm volatile("s_waitcnt vmcnt(0)" ::: "memory"); }
        if (h < 7) __builtin_amdgcn_s_barrier();
    }

    M3_ST1(0);
    #pragma unroll
    for (int mf = 0; mf < 8; ++mf) {
        #pragma unroll
        for (int nf = 0; nf < 2; ++nf) {
            ushort4 o;
            o.x = f2b(eluf(acc0[mf][nf][0] + bb1[nf].x));
            o.y = f2b(eluf(acc0[mf][nf][1] + bb1[nf].y));
            o.z = f2b(eluf(acc0[mf][nf][2] + bb1[nf].z));
            o.w = f2b(eluf(acc0[mf][nf][3] + bb1[nf].w));
            int lanew = r16 + 16 * ((nf << 1) | (kq >> 1));
            *(ushort4*)&H1[mf][w][lanew * 8 + (kq & 1) * 4] = o;
            acc0[mf][nf] = (f32x4){0.f, 0.f, 0.f, 0.f};
        }
    }
    asm volatile("s_waitcnt lgkmcnt(0)" ::: "memory");
    asm volatile("s_waitcnt vmcnt(0)" ::: "memory");
    __builtin_amdgcn_s_barrier();

    for (int h = 0; h < 8; ++h) {
        if (h + 1 < 8) M3_ST1(h + 1);
        const int sl = h & 1;
        bf16x8 af[8], bfr[2];
        #pragma unroll
        for (int mf = 0; mf < 8; ++mf)
            af[mf] = *(const bf16x8*)&H1[mf][h][lane * 8];
        #pragma unroll
        for (int nf = 0; nf < 2; ++nf)
            bfr[nf] = *(const bf16x8*)&slots[sl * 8192 + (2 * w + nf) * 512 + lane * 8];
        #pragma unroll
        for (int mf = 0; mf < 8; ++mf)
            #pragma unroll
            for (int nf = 0; nf < 2; ++nf)
                acc0[mf][nf] = __builtin_amdgcn_mfma_f32_16x16x32_bf16(bfr[nf], af[mf], acc0[mf][nf], 0, 0, 0);
        asm volatile("s_waitcnt lgkmcnt(0)" ::: "memory");
        if (h + 1 < 8) { asm volatile("s_waitcnt vmcnt(0)" ::: "memory"); }
        if (h < 7) __builtin_amdgcn_s_barrier();
    }

    #pragma unroll
    for (int mf = 0; mf < 8; ++mf) {
        int row = m0 + mf * 16 + r16;
        #pragma unroll
        for (int nf = 0; nf < 2; ++nf) {
            int col = w * 32 + nf * 16 + kq * 4;
            ushort4 o;
            o.x = f2b(eluf(acc0[mf][nf][0] + bb2[nf].x));
            o.y = f2b(eluf(acc0[mf][nf][1] + bb2[nf].y));
            o.z = f2b(eluf(acc0[mf][nf][2] + bb2[nf].z));
            o.w = f2b(eluf(acc0[mf][nf][3] + bb2[nf].w));
            *(ushort4*)&Out[(size_t)row * 256 + col] = o;
        }
    }
#undef M3_ST0
#undef M3_ST1
}

// ===========================================================================
// weights f32 -> bf16 (packed):
// ef_w2 | m4_w1 | m4_w2 | f_wih | r_wih | e_w1 | m3_w1 | m3_w2
// ===========================================================================
__global__ __launch_bounds__(256) void wconv_k(
    const float* __restrict__ ef_w2, const float* __restrict__ m4_w1,
    const float* __restrict__ m4_w2, const float* __restrict__ f_wih,
    const float* __restrict__ r_wih, const float* __restrict__ e_w1,
    const float* __restrict__ m3_w1, const float* __restrict__ m3_w2,
    ushort_t* __restrict__ Wb)
{
    int i = blockIdx.x * 256 + threadIdx.x;   // < 622592
    const float* src; int off;
    if (i < 65536)       { src = ef_w2; off = i; }
    else if (i < 262144) { src = m4_w1; off = i - 65536; }
    else if (i < 327680) { src = m4_w2; off = i - 262144; }
    else if (i < 393216) { src = f_wih; off = i - 327680; }
    else if (i < 458752) { src = r_wih; off = i - 393216; }
    else if (i < 491520) { src = e_w1;  off = i - 458752; }
    else if (i < 557056) { src = m3_w1; off = i - 491520; }
    else                 { src = m3_w2; off = i - 557056; }
    Wb[i] = f2b(src[off]);
}

// ---------------------------------------------------------------------------
// edge2node: X[b,v,t,h] = (1/15)*sum_{e:RECV==v} EA[b,e,t,h] + rel@res_w.T + res_b
// Output bf16 (feeds MFMA mlp3).
// ---------------------------------------------------------------------------
__global__ __launch_bounds__(256) void e2n_k(
    const ushort_t* __restrict__ EA, const float* __restrict__ rel,
    const float* __restrict__ res_w, const float* __restrict__ res_b,
    ushort_t* __restrict__ X)
{
    const int idx = blockIdx.x;            // (b*V+v)*T + t
    const int t = idx & (T_ - 1);
    const int bv = idx >> 6;
    const int v = bv & (V_ - 1);
    const int b = bv >> 4;
    const int h = threadIdx.x;
    float sum = 0.f;
    #pragma unroll
    for (int i = 0; i < V_; ++i) {
        if (i == v) continue;
        int jj = (v < i) ? v : v - 1;
        int e = i * (V_ - 1) + jj;
        sum += b2f(EA[(((size_t)(b * E_ + e)) * T_ + t) * H_ + h]);
    }
    const float* rp = rel + ((size_t)bv * T_ + t) * DIN_;
    float res = res_b[h];
    #pragma unroll
    for (int d = 0; d < DIN_; ++d) res += rp[d] * res_w[h * DIN_ + d];
    X[((size_t)bv * T_ + t) * H_ + h] = f2b(sum * (1.f / 15.f) + res);
}

// ===========================================================================
// MFMA LSTM scan, both directions in one dispatch (blockIdx.y = dir).
// ===========================================================================
__global__ __launch_bounds__(256) void lstm_mfma4_k(
    const ushort_t* __restrict__ Gf, const ushort_t* __restrict__ Gr,
    const float* __restrict__ whh_f, const float* __restrict__ whh_r,
    ushort_t* __restrict__ COMB)
{
    __shared__ ushort_t hlds[2][1024];   // 2 x 2KB: h[seq][j] bf16, XOR-swizzled
    const int dir = blockIdx.y;
    const ushort_t* G = dir ? Gr : Gf;
    const float* whh = dir ? whh_r : whh_f;
    const int tid = threadIdx.x;
    const int lane = tid & 63;
    const int w = tid >> 6;              // wave id = j-block
    const int seq = lane & 15, kq = lane >> 4;
    const int be0 = blockIdx.x * 16;
    const int swz = (seq & 7) << 4;

    bf16x8 wf[4][2];
    #pragma unroll
    for (int a = 0; a < 4; ++a) {
        #pragma unroll
        for (int ks = 0; ks < 2; ++ks) {
            const float* p = whh + (size_t)((a * 4 + w) * 16 + seq) * 64 + ks * 32 + kq * 8;
            float4 x0 = *(const float4*)p;
            float4 x1 = *(const float4*)(p + 4);
            bf16x8 v;
            v[0] = (short)f2b(x0.x); v[1] = (short)f2b(x0.y);
            v[2] = (short)f2b(x0.z); v[3] = (short)f2b(x0.w);
            v[4] = (short)f2b(x1.x); v[5] = (short)f2b(x1.y);
            v[6] = (short)f2b(x1.z); v[7] = (short)f2b(x1.w);
            wf[a][ks] = v;
        }
    }

    const ushort_t* grow = G + ((size_t)(be0 + seq) * T_) * 256 + kq * 4;
    ushort_t* crow = COMB + ((size_t)(be0 + seq) * T_) * 128 + (dir ? 64 : 0) + 16 * w + 4 * kq;

    float c[4] = {};
    ushort4 gx[4];
    const int t0 = dir ? (T_ - 1) : 0;
    #pragma unroll
    for (int a = 0; a < 4; ++a)
        gx[a] = *(const ushort4*)(grow + (size_t)t0 * 256 + (a * 4 + w) * 16);

    for (int s = 0; s < T_; ++s) {
        const int t = dir ? (T_ - 1 - s) : s;
        f32x4 acc[4];
        #pragma unroll
        for (int a = 0; a < 4; ++a) {
            ushort4 g = gx[a];
            acc[a] = (f32x4){b2f(g.x), b2f(g.y), b2f(g.z), b2f(g.w)};
        }
        if (s < T_ - 1) {
            const int tn = dir ? (T_ - 2 - s) : (s + 1);
            #pragma unroll
            for (int a = 0; a < 4; ++a)
                gx[a] = *(const ushort4*)(grow + (size_t)tn * 256 + (a * 4 + w) * 16);
        }
        if (s) {
            bf16x8 af[2];
            #pragma unroll
            for (int ks = 0; ks < 2; ++ks) {
                int boff = (seq * 128 + ks * 64 + kq * 16) ^ swz;
                af[ks] = *(const bf16x8*)((const char*)hlds[(s - 1) & 1] + boff);
            }
            #pragma unroll
            for (int a = 0; a < 4; ++a) {
                acc[a] = __builtin_amdgcn_mfma_f32_16x16x32_bf16(wf[a][0], af[0], acc[a], 0, 0, 0);
                acc[a] = __builtin_amdgcn_mfma_f32_16x16x32_bf16(wf[a][1], af[1], acc[a], 0, 0, 0);
            }
        }
        float hh[4];
        #pragma unroll
        for (int r = 0; r < 4; ++r) {
            float zi = acc[0][r], zf = acc[1][r], zg = acc[2][r], zo = acc[3][r];
            float cc = fsig(zf) * c[r] + fsig(zi) * ftanh_(zg);
            c[r] = cc;
            hh[r] = fsig(zo) * ftanh_(cc);
        }
        ushort4 hv;
        hv.x = f2b(hh[0]); hv.y = f2b(hh[1]); hv.z = f2b(hh[2]); hv.w = f2b(hh[3]);
        int wb = (seq * 128 + 32 * w + 8 * kq) ^ swz;
        *(ushort4*)((char*)hlds[s & 1] + wb) = hv;
        *(ushort4*)(crow + (size_t)t * 128) = hv;
        asm volatile("s_waitcnt lgkmcnt(0)" ::: "memory");
        __builtin_amdgcn_sched_barrier(0);
        __builtin_amdgcn_s_barrier();
    }
}

// ---------------------------------------------------------------------------
// prior head: reads fwd hidden from comb[:, 0:64] (row stride 128)
// ---------------------------------------------------------------------------
__global__ __launch_bounds__(256) void prior_k(
    const ushort_t* __restrict__ COMB, const float* __restrict__ p_w,
    const float* __restrict__ p_b, float* __restrict__ out)
{
    const int row = blockIdx.x * 4 + (threadIdx.x >> 6);  // [0, BET)
    const int lane = threadIdx.x & 63;
    float hf = b2f(COMB[(size_t)row * 128 + lane]);
    float v0 = hf * p_w[lane];
    float v1 = hf * p_w[64 + lane];
    #pragma unroll
    for (int off = 32; off > 0; off >>= 1) {
        v0 += __shfl_down(v0, off, 64);
        v1 += __shfl_down(v1, off, 64);
    }
    if (lane == 0) {
        int t = row & (T_ - 1);
        int be = row >> 6;
        int e = be % E_, b = be / E_;
        size_t o = (((size_t)b * T_ + t) * E_ + e) * K_;
        out[o] = v0 + p_b[0];
        out[o + 1] = v1 + p_b[1];
    }
}

// ===========================================================================
// FUSED: ENCH = elu(COMB@e_w1.T + e_b1) in regs, then out = ENCH@e_w2.T + e_b2
// (unchanged from round 9-13)
// ===========================================================================
__global__ __launch_bounds__(512) void fused_enc_k(
    const ushort_t* __restrict__ COMB, const ushort_t* __restrict__ w_e1,
    const float* __restrict__ e_b1, const float* __restrict__ e_w2,
    const float* __restrict__ e_b2, float* __restrict__ out)
{
    __shared__ ushort_t sA[2][8][512];    // 16 KB
    __shared__ ushort_t sW[2][16][512];   // 32 KB
    __shared__ float part[128][4][2];     // 4 KB
    const int tid = threadIdx.x;
    const int lane = tid & 63;
    const int w = tid >> 6;
    const int wr = w >> 2, wc = w & 3;
    const int m0 = blockIdx.x * 128;
    const int r16 = lane & 15, kq = lane >> 4;

    const ushort_t* Asrc = COMB + (size_t)(m0 + w * 16 + r16) * 128 + kq * 8;
    const size_t woffA = (size_t)((2 * w) * 16 + r16) * 128 + kq * 8;
    const size_t woffB = (size_t)((2 * w + 1) * 16 + r16) * 128 + kq * 8;

    float4 w2v[2][4];
    #pragma unroll
    for (int j = 0; j < 2; ++j)
        #pragma unroll
        for (int nf = 0; nf < 4; ++nf)
            w2v[j][nf] = *(const float4*)&e_w2[j * 256 + wc * 64 + nf * 16 + kq * 4];

    f32x4 acc[4][4];
    #pragma unroll
    for (int i = 0; i < 4; ++i)
        #pragma unroll
        for (int j = 0; j < 4; ++j)
            acc[i][j] = (f32x4){0.f, 0.f, 0.f, 0.f};

#define FE_STAGE(bufi, kt_) do {                                             \
    gll16(Asrc + (kt_) * 32, &sA[bufi][w][0]);                               \
    gll16(w_e1 + woffA + (kt_) * 32, &sW[bufi][2 * w][0]);                   \
    gll16(w_e1 + woffB + (kt_) * 32, &sW[bufi][2 * w + 1][0]);               \
} while (0)

    FE_STAGE(0, 0);
    asm volatile("s_waitcnt vmcnt(0)" ::: "memory");
    __builtin_amdgcn_s_barrier();

    for (int s = 0; s < 4; ++s) {
        const int buf = s & 1;
        if (s < 3) FE_STAGE(buf ^ 1, s + 1);
        bf16x8 af[4], bfr[4];
        #pragma unroll
        for (int mf = 0; mf < 4; ++mf)
            af[mf] = *(const bf16x8*)&sA[buf][wr * 4 + mf][lane * 8];
        #pragma unroll
        for (int nf = 0; nf < 4; ++nf)
            bfr[nf] = *(const bf16x8*)&sW[buf][wc * 4 + nf][lane * 8];
        #pragma unroll
        for (int mf = 0; mf < 4; ++mf)
            #pragma unroll
            for (int nf = 0; nf < 4; ++nf)
                acc[mf][nf] = __builtin_amdgcn_mfma_f32_16x16x32_bf16(bfr[nf], af[mf], acc[mf][nf], 0, 0, 0);
        asm volatile("s_waitcnt vmcnt(0)" ::: "memory");
        __builtin_amdgcn_s_barrier();
    }

    #pragma unroll
    for (int mf = 0; mf < 4; ++mf) {
        float s0 = 0.f, s1 = 0.f;
        #pragma unroll
        for (int nf = 0; nf < 4; ++nf) {
            int col = wc * 64 + nf * 16 + kq * 4;
            float4 bb = *(const float4*)&e_b1[col];
            float v0 = eluf(acc[mf][nf][0] + bb.x);
            float v1 = eluf(acc[mf][nf][1] + bb.y);
            float v2 = eluf(acc[mf][nf][2] + bb.z);
            float v3 = eluf(acc[mf][nf][3] + bb.w);
            s0 += v0 * w2v[0][nf].x + v1 * w2v[0][nf].y + v2 * w2v[0][nf].z + v3 * w2v[0][nf].w;
            s1 += v0 * w2v[1][nf].x + v1 * w2v[1][nf].y + v2 * w2v[1][nf].z + v3 * w2v[1][nf].w;
        }
        s0 += __shfl_xor(s0, 16, 64); s0 += __shfl_xor(s0, 32, 64);
        s1 += __shfl_xor(s1, 16, 64); s1 += __shfl_xor(s1, 32, 64);
        if (kq == 0) {
            part[wr * 64 + mf * 16 + r16][wc][0] = s0;
            part[wr * 64 + mf * 16 + r16][wc][1] = s1;
        }
    }
    __syncthreads();
    if (tid < 256) {
        int row = tid >> 1, k = tid & 1;
        float v = part[row][0][k] + part[row][1][k] + part[row][2][k] + part[row][3][k] + e_b2[k];
        int gr = m0 + row;
        int be = gr >> 6, t = gr & 63;
        int e = be % E_, b = be / E_;
        out[(size_t)(B_ * T_ * E_ * K_) + (((size_t)b * T_ + t) * E_ + e) * K_ + k] = v;
    }
#undef FE_STAGE
}

// ---------------------------------------------------------------------------
extern "C" void kernel_launch(void* const* d_in, const int* in_sizes, int n_in,
                              void* d_out, int out_size, void* d_ws, size_t ws_size,
                              hipStream_t stream)
{
    const float* rel    = (const float*)d_in[0];
    const float* ear    = (const float*)d_in[1];
    const float* epos   = (const float*)d_in[2];
    const float* ef_w1  = (const float*)d_in[3];
    const float* ef_b1  = (const float*)d_in[4];
    const float* ef_w2  = (const float*)d_in[5];
    const float* ef_b2  = (const float*)d_in[6];
    const float* res_w  = (const float*)d_in[7];
    const float* res_b  = (const float*)d_in[8];
    const float* m3_w1  = (const float*)d_in[9];
    const float* m3_b1  = (const float*)d_in[10];
    const float* m3_w2  = (const float*)d_in[11];
    const float* m3_b2  = (const float*)d_in[12];
    const float* m4_w1  = (const float*)d_in[13];
    const float* m4_b1  = (const float*)d_in[14];
    const float* m4_w2  = (const float*)d_in[15];
    const float* m4_b2  = (const float*)d_in[16];
    const float* f_wih  = (const float*)d_in[17];
    const float* f_whh  = (const float*)d_in[18];
    const float* f_bih  = (const float*)d_in[19];
    const float* f_bhh  = (const float*)d_in[20];
    const float* r_wih  = (const float*)d_in[21];
    const float* r_whh  = (const float*)d_in[22];
    const float* r_bih  = (const float*)d_in[23];
    const float* r_bhh  = (const float*)d_in[24];
    const float* p_w    = (const float*)d_in[25];
    const float* p_b    = (const float*)d_in[26];
    const float* e_w1   = (const float*)d_in[27];
    const float* e_b1   = (const float*)d_in[28];
    const float* e_w2   = (const float*)d_in[29];
    const float* e_b2   = (const float*)d_in[30];
    float* out = (float*)d_out;

    // workspace layout (bytes), total ~163 MB
    char* ws = (char*)d_ws;
    const size_t BIGB  = (size_t)BET_ * H_ * sizeof(ushort_t);   // 62,914,560
    const size_t COMBB = (size_t)BET_ * 128 * sizeof(ushort_t);  // 31,457,280
    const size_t X2BB  = (size_t)BVT_ * H_ * sizeof(ushort_t);   //  4,194,304
    ushort_t* R1   = (ushort_t*)(ws);
    ushort_t* R2   = (ushort_t*)(ws + BIGB);
    ushort_t* COMB = (ushort_t*)(ws + 2 * BIGB);
    ushort_t* X2b  = (ushort_t*)(ws + 2 * BIGB + COMBB);
    ushort_t* Wb   = (ushort_t*)(ws + 2 * BIGB + COMBB + X2BB);
    // node-stage bf16 X lives inside (dead) R1 region
    ushort_t* Xbf = (ushort_t*)(ws);
    // packed bf16 weight offsets (elements)
    const ushort_t* wb_ef2  = Wb + 0;
    const ushort_t* wb_m41  = Wb + 65536;
    const ushort_t* wb_m42  = Wb + 262144;
    const ushort_t* wb_fwih = Wb + 327680;
    const ushort_t* wb_rwih = Wb + 393216;
    const ushort_t* wb_ew1  = Wb + 458752;
    const ushort_t* wb_m31  = Wb + 491520;
    const ushort_t* wb_m32  = Wb + 557056;

    dim3 blk(256);
    dim3 blk8(512);
    dim3 blk16(1024);
    dim3 g128(BET_ / 128);     // 960 blocks (BM=128 kernels)
    dim3 g512(BET_ / 512);     // 240 blocks (BM=512 kernels, single round)
    dim3 gE64(BET_ / 64, 4);   // VALU ein GEMM

    // 0. weights -> bf16 (incl. mlp3)
    wconv_k<<<2432, blk, 0, stream>>>(ef_w2, m4_w1, m4_w2, f_wih, r_wih, e_w1, m3_w1, m3_w2, Wb);
    // 1. edge-filter MLP: VALU ein (K=16) -> R1, then MFMA ef2 -> R2 (EA)
    gemm_ein_k<<<gE64, blk, 0, stream>>>(ear, epos, ef_w1, ef_b1, R1);
    gemm16_k<256, 1><<<g512, blk16, 0, stream>>>(R1, wb_ef2, ef_b2, nullptr, R2);
    // 2. edge2node + residual -> bf16 X (aliases R1; H1 dead)
    e2n_k<<<BVT_, blk, 0, stream>>>(R2, rel, res_w, res_b, Xbf);
    // 3. fused mlp3 (both layers, MFMA) -> X2b
    gemm8_mlp3_k<<<BVT_ / 128, blk8, 0, stream>>>(Xbf, wb_m31, m3_b1, wb_m32, m3_b2, X2b);
    // 4. node2edge gather + mlp4 layer 1 -> T1 (R1)
    gemm16_mlp4_k<<<g512, blk16, 0, stream>>>(X2b, R2, wb_m41, m4_b1, R1);
    // 5. m4l2 + gate GEMMs (BM=512 single-round):
    //    M2: R1 -> R2; GF: R2 -> R1; GR: R2 -> R2 (in-place, per-block rows)
    gemm16_k<256, 1><<<g512, blk16, 0, stream>>>(R1, wb_m42, m4_b2, nullptr, R2);
    gemm16_k<256, 0><<<g512, blk16, 0, stream>>>(R2, wb_fwih, f_bih, f_bhh, R1);
    gemm16_k<256, 0><<<g512, blk16, 0, stream>>>(R2, wb_rwih, r_bih, r_bhh, R2);
    // 6. LSTM scans, both directions in one dispatch (Gf=R1, Gr=R2)
    lstm_mfma4_k<<<dim3(BE_ / 16, 2), blk, 0, stream>>>(R1, R2, f_whh, r_whh, COMB);
    // 7. heads
    prior_k<<<BET_ / 4, blk, 0, stream>>>(COMB, p_w, p_b, out);
    fused_enc_k<<<g128, blk8, 0, stream>>>(COMB, wb_ew1, e_b1, e_w2, e_b2, out);
}

// Round 15
// 404.076 us; speedup vs baseline: 3.3294x; 3.3294x over previous
//
#include <hip/hip_runtime.h>
#include <cstdint>
#include <cstddef>
#include <type_traits>

// Problem constants
#define B_ 8
#define V_ 16
#define T_ 64
#define E_ 240          // V*(V-1)
#define H_ 256
#define RH_ 64
#define K_ 2
#define DIN_ 6
#define BET_ (B_*E_*T_)   // 122880
#define BVT_ (B_*V_*T_)   // 8192
#define BE_ (B_*E_)       // 1920

typedef unsigned short ushort_t;
typedef unsigned int u32;
typedef __attribute__((ext_vector_type(8))) short bf16x8;
typedef __attribute__((ext_vector_type(4))) float f32x4;

__device__ __forceinline__ float eluf(float x) { return x > 0.f ? x : __expf(x) - 1.f; }
__device__ __forceinline__ float fsig(float x) { return 1.f / (1.f + __expf(-x)); }
__device__ __forceinline__ float ftanh_(float x) {
    float y = fminf(fmaxf(x, -8.f), 8.f);
    float e = __expf(2.f * y);
    return (e - 1.f) / (e + 1.f);
}
__device__ __forceinline__ float b2f(ushort_t u) {
    union { float f; uint32_t i; } v; v.i = ((uint32_t)u) << 16; return v.f;
}
__device__ __forceinline__ ushort_t f2b(float f) {
    union { float f; uint32_t i; } v; v.f = f;
    uint32_t r = (v.i + 0x7FFFu + ((v.i >> 16) & 1u)) >> 16;
    return (ushort_t)r;
}

// async global->LDS, 16B per lane; LDS dest = wave-uniform base + lane*16
__device__ __forceinline__ void gll16(const void* g, void* l) {
    __builtin_amdgcn_global_load_lds(
        (const __attribute__((address_space(1))) u32*)g,
        (__attribute__((address_space(3))) u32*)l, 16, 0, 0);
}

// ===========================================================================
// 8-wave half-tile-pipelined MFMA GEMM (r8-proven): C = act(A@W.T + b1 (+b2))
// BM=256, BN=256(=N), wave-tile 128x64 via mh-split, K-half=32, 4 LDS slots,
// counted vmcnt(8/4/0). In-place safe for per-block rows.
// ===========================================================================
template<int KD, int ACT>
__global__ __launch_bounds__(512, 2) void gemm8_k(
    const ushort_t* __restrict__ A, const ushort_t* __restrict__ Wt,
    const float* __restrict__ b1, const float* __restrict__ b2,
    ushort_t* __restrict__ C)
{
    __shared__ ushort_t lds[4][32][512];   // 128 KB
    const int tid = threadIdx.x;
    const int lane = tid & 63;
    const int w = tid >> 6;                // 0..7
    const int wm = w >> 2, wn = w & 3;     // 2m x 4n
    const int m0 = blockIdx.x * 256;
    const int r16 = lane & 15, kq = lane >> 4;
    constexpr int NH = KD / 32;

    const ushort_t* Ag0 = A + (size_t)(m0 + w * 16 + r16) * KD + kq * 8;
    const ushort_t* Ag1 = A + (size_t)(m0 + (w + 8) * 16 + r16) * KD + kq * 8;
    const ushort_t* Bg0 = Wt + (size_t)(w * 16 + r16) * KD + kq * 8;
    const ushort_t* Bg1 = Wt + (size_t)((w + 8) * 16 + r16) * KD + kq * 8;

    f32x4 acc[8][4];
    #pragma unroll
    for (int i = 0; i < 8; ++i)
        #pragma unroll
        for (int j = 0; j < 4; ++j)
            acc[i][j] = (f32x4){0.f, 0.f, 0.f, 0.f};

#define ST8(h) do { int sl_ = (h) & 3; int kk_ = (h) * 32;                  \
    gll16(Ag0 + kk_, &lds[sl_][w][0]);                                      \
    gll16(Ag1 + kk_, &lds[sl_][w + 8][0]);                                  \
    gll16(Bg0 + kk_, &lds[sl_][16 + w][0]);                                 \
    gll16(Bg1 + kk_, &lds[sl_][16 + w + 8][0]);                             \
} while (0)

    ST8(0); ST8(1); ST8(2);
    asm volatile("s_waitcnt vmcnt(8)" ::: "memory");   // half 0 landed
    __builtin_amdgcn_s_barrier();

    for (int h = 0; h < NH; ++h) {
        if (h + 3 < NH) ST8(h + 3);
        const int sl = h & 3;
        bf16x8 bfr[4];
        #pragma unroll
        for (int nf = 0; nf < 4; ++nf)
            bfr[nf] = *(const bf16x8*)&lds[sl][16 + wn * 4 + nf][lane * 8];
        #pragma unroll
        for (int mh = 0; mh < 2; ++mh) {
            bf16x8 af[4];
            #pragma unroll
            for (int mf = 0; mf < 4; ++mf)
                af[mf] = *(const bf16x8*)&lds[sl][wm * 8 + mh * 4 + mf][lane * 8];
            __builtin_amdgcn_s_setprio(1);
            #pragma unroll
            for (int mf = 0; mf < 4; ++mf)
                #pragma unroll
                for (int nf = 0; nf < 4; ++nf)
                    acc[mh * 4 + mf][nf] = __builtin_amdgcn_mfma_f32_16x16x32_bf16(
                        bfr[nf], af[mf], acc[mh * 4 + mf][nf], 0, 0, 0);
            __builtin_amdgcn_s_setprio(0);
        }
        asm volatile("s_waitcnt lgkmcnt(0)" ::: "memory");  // my reads of slot done
        if (h < NH - 3)       { asm volatile("s_waitcnt vmcnt(8)" ::: "memory"); }
        else if (h == NH - 3) { asm volatile("s_waitcnt vmcnt(4)" ::: "memory"); }
        else if (h == NH - 2) { asm volatile("s_waitcnt vmcnt(0)" ::: "memory"); }
        if (h < NH - 1) __builtin_amdgcn_s_barrier();
    }
#undef ST8

    #pragma unroll
    for (int mi = 0; mi < 8; ++mi) {
        int mrow = m0 + wm * 128 + mi * 16 + r16;
        #pragma unroll
        for (int nf = 0; nf < 4; ++nf) {
            int nb = wn * 64 + nf * 16 + kq * 4;
            float4 bb = *(const float4*)&b1[nb];
            if (b2) {
                float4 b2v = *(const float4*)&b2[nb];
                bb.x += b2v.x; bb.y += b2v.y; bb.z += b2v.z; bb.w += b2v.w;
            }
            float v0 = acc[mi][nf][0] + bb.x;
            float v1 = acc[mi][nf][1] + bb.y;
            float v2 = acc[mi][nf][2] + bb.z;
            float v3 = acc[mi][nf][3] + bb.w;
            if (ACT) { v0 = eluf(v0); v1 = eluf(v1); v2 = eluf(v2); v3 = eluf(v3); }
            ushort4 o; o.x = f2b(v0); o.y = f2b(v1); o.z = f2b(v2); o.w = f2b(v3);
            *(ushort4*)&C[(size_t)mrow * 256 + nb] = o;
        }
    }
}

// ===========================================================================
// GF+GR merged GEMM: BM=128, N=512 ([fih|rih]), KD=256 (8 halves).
// Wave w (0..7): cols 64*(w&3) of (w<4 ? GF : GR). acc[8][4] + mh-split.
// 3 LDS slots x 40KB = 120 KB. 5 loads/wave/half; counted vmcnt(5), 0 at tail.
// GR may be in-place over A (per-block rows; A loads all landed by h=NH-2).
// ===========================================================================
__global__ __launch_bounds__(512, 1) void gemm8_gates_k(
    const ushort_t* __restrict__ A, const ushort_t* __restrict__ w_fih,
    const ushort_t* __restrict__ w_rih,
    const float* __restrict__ f_bih, const float* __restrict__ f_bhh,
    const float* __restrict__ r_bih, const float* __restrict__ r_bhh,
    ushort_t* __restrict__ GF, ushort_t* __restrict__ GR)
{
    __shared__ ushort_t lds[3][40][512];   // 120 KB: entries 0-7 A, 8-39 B
    const int tid = threadIdx.x;
    const int lane = tid & 63;
    const int w = tid >> 6;
    const int m0 = blockIdx.x * 128;
    const int r16 = lane & 15, kq = lane >> 4;
    constexpr int NH = 8;

    const ushort_t* Ag = A + (size_t)(m0 + w * 16 + r16) * 256 + kq * 8;
    const ushort_t* WB = (w < 4) ? w_fih : w_rih;
    const int cb = (w & 3) * 64;           // col base within its gate matrix

    const float* bi = (w < 4) ? f_bih : r_bih;
    const float* bh = (w < 4) ? f_bhh : r_bhh;
    float4 bg[4];
    #pragma unroll
    for (int nf = 0; nf < 4; ++nf) {
        int col = cb + nf * 16 + kq * 4;
        float4 a = *(const float4*)&bi[col];
        float4 b = *(const float4*)&bh[col];
        bg[nf] = (float4){a.x + b.x, a.y + b.y, a.z + b.z, a.w + b.w};
    }

    f32x4 acc[8][4];
    #pragma unroll
    for (int i = 0; i < 8; ++i)
        #pragma unroll
        for (int j = 0; j < 4; ++j)
            acc[i][j] = (f32x4){0.f, 0.f, 0.f, 0.f};

#define GST(h) do { int sl_ = (h) % 3; int kk_ = (h) * 32;                  \
    gll16(Ag + kk_, &lds[sl_][w][0]);                                       \
    _Pragma("unroll")                                                       \
    for (int j = 0; j < 4; ++j)                                             \
        gll16(WB + (size_t)(cb + j * 16 + r16) * 256 + kq * 8 + kk_,        \
              &lds[sl_][8 + 4 * w + j][0]);                                 \
} while (0)

    GST(0); GST(1);
    asm volatile("s_waitcnt vmcnt(5)" ::: "memory");   // half 0 landed
    __builtin_amdgcn_s_barrier();

    for (int h = 0; h < NH; ++h) {
        if (h + 2 < NH) GST(h + 2);
        const int sl = h % 3;
        bf16x8 bfr[4];
        #pragma unroll
        for (int nf = 0; nf < 4; ++nf)
            bfr[nf] = *(const bf16x8*)&lds[sl][8 + 4 * w + nf][lane * 8];
        #pragma unroll
        for (int mh = 0; mh < 2; ++mh) {
            bf16x8 af[4];
            #pragma unroll
            for (int mf = 0; mf < 4; ++mf)
                af[mf] = *(const bf16x8*)&lds[sl][mh * 4 + mf][lane * 8];
            __builtin_amdgcn_s_setprio(1);
            #pragma unroll
            for (int mf = 0; mf < 4; ++mf)
                #pragma unroll
                for (int nf = 0; nf < 4; ++nf)
                    acc[mh * 4 + mf][nf] = __builtin_amdgcn_mfma_f32_16x16x32_bf16(
                        bfr[nf], af[mf], acc[mh * 4 + mf][nf], 0, 0, 0);
            __builtin_amdgcn_s_setprio(0);
        }
        asm volatile("s_waitcnt lgkmcnt(0)" ::: "memory");
        if (h <= NH - 3)      { asm volatile("s_waitcnt vmcnt(5)" ::: "memory"); }
        else if (h == NH - 2) { asm volatile("s_waitcnt vmcnt(0)" ::: "memory"); }
        if (h < NH - 1) __builtin_amdgcn_s_barrier();
    }
#undef GST

    ushort_t* Wout = (w < 4) ? GF : GR;
    #pragma unroll
    for (int mi = 0; mi < 8; ++mi) {
        int mrow = m0 + mi * 16 + r16;
        #pragma unroll
        for (int nf = 0; nf < 4; ++nf) {
            int col = cb + nf * 16 + kq * 4;
            ushort4 o;
            o.x = f2b(acc[mi][nf][0] + bg[nf].x);
            o.y = f2b(acc[mi][nf][1] + bg[nf].y);
            o.z = f2b(acc[mi][nf][2] + bg[nf].z);
            o.w = f2b(acc[mi][nf][3] + bg[nf].w);
            *(ushort4*)&Wout[(size_t)mrow * 256 + col] = o;
        }
    }
}

// ===========================================================================
// VALU ein GEMM (r2-proven): H1 = elu(concat(ear,epos)@ef_w1.T + b1), Kd=16.
// ===========================================================================
__global__ __launch_bounds__(256) void gemm_ein_k(
    const float* __restrict__ ear, const float* __restrict__ epos,
    const float* __restrict__ W, const float* __restrict__ b1,
    ushort_t* __restrict__ C)
{
    __shared__ float As[16][64];
    __shared__ float Ws[16][64];
    const int m0 = blockIdx.x * 64, n0 = blockIdx.y * 64;
    const int tid = threadIdx.x;
    const int tm = tid >> 4, tn = tid & 15;
    const int lm = tid >> 2, lq = tid & 3;
    const int m = m0 + lm;
    float a_[4];
    #pragma unroll
    for (int q = 0; q < 4; ++q) {
        int c = lq * 4 + q;
        a_[q] = (c < 13) ? ear[(size_t)m * 13 + c] : epos[(size_t)m * 3 + (c - 13)];
    }
    float4 wv = *(const float4*)(W + (size_t)(n0 + lm) * 16 + lq * 4);
    As[lq*4+0][lm] = a_[0]; As[lq*4+1][lm] = a_[1]; As[lq*4+2][lm] = a_[2]; As[lq*4+3][lm] = a_[3];
    Ws[lq*4+0][lm] = wv.x; Ws[lq*4+1][lm] = wv.y; Ws[lq*4+2][lm] = wv.z; Ws[lq*4+3][lm] = wv.w;
    __syncthreads();
    float acc[4][4] = {};
    #pragma unroll
    for (int k = 0; k < 16; ++k) {
        float4 a = *(const float4*)&As[k][tm * 4];
        float4 w = *(const float4*)&Ws[k][tn * 4];
        float aa[4] = {a.x, a.y, a.z, a.w};
        float ww[4] = {w.x, w.y, w.z, w.w};
        #pragma unroll
        for (int i = 0; i < 4; ++i)
            #pragma unroll
            for (int j = 0; j < 4; ++j)
                acc[i][j] += aa[i] * ww[j];
    }
    #pragma unroll
    for (int i = 0; i < 4; ++i) {
        ushort4 o;
        o.x = f2b(eluf(acc[i][0] + b1[n0 + tn*4 + 0]));
        o.y = f2b(eluf(acc[i][1] + b1[n0 + tn*4 + 1]));
        o.z = f2b(eluf(acc[i][2] + b1[n0 + tn*4 + 2]));
        o.w = f2b(eluf(acc[i][3] + b1[n0 + tn*4 + 3]));
        *(ushort4*)(C + (size_t)(m0 + tm * 4 + i) * H_ + (n0 + tn * 4)) = o;
    }
}

// ===========================================================================
// FUSED mlp3 (both layers, node rows) — unchanged from r10 (works)
// ===========================================================================
__global__ __launch_bounds__(512, 1) void gemm8_mlp3_k(
    const ushort_t* __restrict__ Xb, const ushort_t* __restrict__ w1,
    const float* __restrict__ b1, const ushort_t* __restrict__ w2,
    const float* __restrict__ b2, ushort_t* __restrict__ Out)
{
    __shared__ ushort_t H1[8][8][512];   // 64 KB
    __shared__ ushort_t slots[36864];    // 72 KB
    const int tid = threadIdx.x;
    const int lane = tid & 63;
    const int w = tid >> 6;
    const int m0 = blockIdx.x * 128;
    const int r16 = lane & 15, kq = lane >> 4;

    const ushort_t* Ag = Xb + (size_t)(m0 + w * 16 + r16) * 256 + kq * 8;
    const size_t bo0 = (size_t)(2 * w * 16 + r16) * 256 + kq * 8;
    const size_t bo1 = (size_t)((2 * w + 1) * 16 + r16) * 256 + kq * 8;

    float4 bb1[2], bb2[2];
    #pragma unroll
    for (int nf = 0; nf < 2; ++nf) {
        bb1[nf] = *(const float4*)&b1[w * 32 + nf * 16 + kq * 4];
        bb2[nf] = *(const float4*)&b2[w * 32 + nf * 16 + kq * 4];
    }

#define M3_ST0(h) do { int sl_ = (h) % 3;                                   \
    gll16(Ag + (h) * 32, &slots[sl_ * 12288 + w * 512]);                    \
    gll16(w1 + bo0 + (h) * 32, &slots[sl_ * 12288 + 4096 + 2 * w * 512]);   \
    gll16(w1 + bo1 + (h) * 32, &slots[sl_ * 12288 + 4096 + (2 * w + 1) * 512]); \
} while (0)
#define M3_ST1(h) do { int sl_ = (h) & 1; int kk_ = (h) * 32;               \
    gll16(w2 + bo0 + kk_, &slots[sl_ * 8192 + 2 * w * 512]);                \
    gll16(w2 + bo1 + kk_, &slots[sl_ * 8192 + (2 * w + 1) * 512]);          \
} while (0)

    f32x4 acc0[8][2];
    #pragma unroll
    for (int i = 0; i < 8; ++i) { acc0[i][0] = (f32x4){0,0,0,0}; acc0[i][1] = (f32x4){0,0,0,0}; }

    M3_ST0(0); M3_ST0(1);
    asm volatile("s_waitcnt vmcnt(3)" ::: "memory");
    __builtin_amdgcn_s_barrier();

    for (int h = 0; h < 8; ++h) {
        if (h + 2 < 8) M3_ST0(h + 2);
        const int sl = h % 3;
        bf16x8 af[8], bfr[2];
        #pragma unroll
        for (int mf = 0; mf < 8; ++mf)
            af[mf] = *(const bf16x8*)&slots[sl * 12288 + mf * 512 + lane * 8];
        #pragma unroll
        for (int nf = 0; nf < 2; ++nf)
            bfr[nf] = *(const bf16x8*)&slots[sl * 12288 + 4096 + (2 * w + nf) * 512 + lane * 8];
        #pragma unroll
        for (int mf = 0; mf < 8; ++mf)
            #pragma unroll
            for (int nf = 0; nf < 2; ++nf)
                acc0[mf][nf] = __builtin_amdgcn_mfma_f32_16x16x32_bf16(bfr[nf], af[mf], acc0[mf][nf], 0, 0, 0);
        asm volatile("s_waitcnt lgkmcnt(0)" ::: "memory");
        if (h <= 5)      { asm volatile("s_waitcnt vmcnt(3)" ::: "memory"); }
        else if (h == 6) { asm volatile("s_waitcnt vmcnt(0)" ::: "memory"); }
        if (h < 7) __builtin_amdgcn_s_barrier();
    }

    M3_ST1(0);
    #pragma unroll
    for (int mf = 0; mf < 8; ++mf) {
        #pragma unroll
        for (int nf = 0; nf < 2; ++nf) {
            ushort4 o;
            o.x = f2b(eluf(acc0[mf][nf][0] + bb1[nf].x));
            o.y = f2b(eluf(acc0[mf][nf][1] + bb1[nf].y));
            o.z = f2b(eluf(acc0[mf][nf][2] + bb1[nf].z));
            o.w = f2b(eluf(acc0[mf][nf][3] + bb1[nf].w));
            int lanew = r16 + 16 * ((nf << 1) | (kq >> 1));
            *(ushort4*)&H1[mf][w][lanew * 8 + (kq & 1) * 4] = o;
            acc0[mf][nf] = (f32x4){0.f, 0.f, 0.f, 0.f};
        }
    }
    asm volatile("s_waitcnt lgkmcnt(0)" ::: "memory");
    asm volatile("s_waitcnt vmcnt(0)" ::: "memory");
    __builtin_amdgcn_s_barrier();

    for (int h = 0; h < 8; ++h) {
        if (h + 1 < 8) M3_ST1(h + 1);
        const int sl = h & 1;
        bf16x8 af[8], bfr[2];
        #pragma unroll
        for (int mf = 0; mf < 8; ++mf)
            af[mf] = *(const bf16x8*)&H1[mf][h][lane * 8];
        #pragma unroll
        for (int nf = 0; nf < 2; ++nf)
            bfr[nf] = *(const bf16x8*)&slots[sl * 8192 + (2 * w + nf) * 512 + lane * 8];
        #pragma unroll
        for (int mf = 0; mf < 8; ++mf)
            #pragma unroll
            for (int nf = 0; nf < 2; ++nf)
                acc0[mf][nf] = __builtin_amdgcn_mfma_f32_16x16x32_bf16(bfr[nf], af[mf], acc0[mf][nf], 0, 0, 0);
        asm volatile("s_waitcnt lgkmcnt(0)" ::: "memory");
        if (h + 1 < 8) { asm volatile("s_waitcnt vmcnt(0)" ::: "memory"); }
        if (h < 7) __builtin_amdgcn_s_barrier();
    }

    #pragma unroll
    for (int mf = 0; mf < 8; ++mf) {
        int row = m0 + mf * 16 + r16;
        #pragma unroll
        for (int nf = 0; nf < 2; ++nf) {
            int col = w * 32 + nf * 16 + kq * 4;
            ushort4 o;
            o.x = f2b(eluf(acc0[mf][nf][0] + bb2[nf].x));
            o.y = f2b(eluf(acc0[mf][nf][1] + bb2[nf].y));
            o.z = f2b(eluf(acc0[mf][nf][2] + bb2[nf].z));
            o.w = f2b(eluf(acc0[mf][nf][3] + bb2[nf].w));
            *(ushort4*)&Out[(size_t)row * 256 + col] = o;
        }
    }
#undef M3_ST0
#undef M3_ST1
}

// ===========================================================================
// mlp4 layer-1 variant: KD=768, A gathered on the fly (unchanged from r8).
// ===========================================================================
__global__ __launch_bounds__(512, 2) void gemm8_mlp4_k(
    const ushort_t* __restrict__ X2b, const ushort_t* __restrict__ EA,
    const ushort_t* __restrict__ Wt, const float* __restrict__ b1,
    ushort_t* __restrict__ C)
{
    __shared__ ushort_t lds[4][32][512];   // 128 KB
    const int tid = threadIdx.x;
    const int lane = tid & 63;
    const int w = tid >> 6;
    const int wm = w >> 2, wn = w & 3;
    const int m0 = blockIdx.x * 256;
    const int r16 = lane & 15, kq = lane >> 4;
    constexpr int NH = 24;

    const ushort_t* AS[2]; const ushort_t* AR[2]; const ushort_t* AE[2];
    #pragma unroll
    for (int ff = 0; ff < 2; ++ff) {
        int f = w + ff * 8;
        int m = m0 + f * 16 + r16;
        int be = m >> 6, t = m & 63;
        int b = be / E_, e = be % E_;
        int s = e / (V_ - 1);
        int r0 = e % (V_ - 1);
        int rr = r0 + (r0 >= s ? 1 : 0);
        AS[ff] = X2b + ((size_t)((b * V_ + s) * T_ + t)) * H_ + kq * 8;
        AR[ff] = X2b + ((size_t)((b * V_ + rr) * T_ + t)) * H_ + kq * 8;
        AE[ff] = EA + (size_t)m * H_ + kq * 8;
    }
    const ushort_t* Bg0 = Wt + (size_t)(w * 16 + r16) * 768 + kq * 8;
    const ushort_t* Bg1 = Wt + (size_t)((w + 8) * 16 + r16) * 768 + kq * 8;

    f32x4 acc[8][4];
    #pragma unroll
    for (int i = 0; i < 8; ++i)
        #pragma unroll
        for (int j = 0; j < 4; ++j)
            acc[i][j] = (f32x4){0.f, 0.f, 0.f, 0.f};

#define STM(h) do { int sl_ = (h) & 3; int kk_ = (h) * 32;                  \
    int seg_ = kk_ >> 8, off_ = kk_ & 255;                                  \
    const ushort_t* a0_ = (seg_ == 0 ? AS[0] : seg_ == 1 ? AR[0] : AE[0]) + off_; \
    const ushort_t* a1_ = (seg_ == 0 ? AS[1] : seg_ == 1 ? AR[1] : AE[1]) + off_; \
    gll16(a0_, &lds[sl_][w][0]);                                            \
    gll16(a1_, &lds[sl_][w + 8][0]);                                        \
    gll16(Bg0 + kk_, &lds[sl_][16 + w][0]);                                 \
    gll16(Bg1 + kk_, &lds[sl_][16 + w + 8][0]);                             \
} while (0)

    STM(0); STM(1); STM(2);
    asm volatile("s_waitcnt vmcnt(8)" ::: "memory");
    __builtin_amdgcn_s_barrier();

    for (int h = 0; h < NH; ++h) {
        if (h + 3 < NH) STM(h + 3);
        const int sl = h & 3;
        bf16x8 bfr[4];
        #pragma unroll
        for (int nf = 0; nf < 4; ++nf)
            bfr[nf] = *(const bf16x8*)&lds[sl][16 + wn * 4 + nf][lane * 8];
        #pragma unroll
        for (int mh = 0; mh < 2; ++mh) {
            bf16x8 af[4];
            #pragma unroll
            for (int mf = 0; mf < 4; ++mf)
                af[mf] = *(const bf16x8*)&lds[sl][wm * 8 + mh * 4 + mf][lane * 8];
            __builtin_amdgcn_s_setprio(1);
            #pragma unroll
            for (int mf = 0; mf < 4; ++mf)
                #pragma unroll
                for (int nf = 0; nf < 4; ++nf)
                    acc[mh * 4 + mf][nf] = __builtin_amdgcn_mfma_f32_16x16x32_bf16(
                        bfr[nf], af[mf], acc[mh * 4 + mf][nf], 0, 0, 0);
            __builtin_amdgcn_s_setprio(0);
        }
        asm volatile("s_waitcnt lgkmcnt(0)" ::: "memory");
        if (h < NH - 3)       { asm volatile("s_waitcnt vmcnt(8)" ::: "memory"); }
        else if (h == NH - 3) { asm volatile("s_waitcnt vmcnt(4)" ::: "memory"); }
        else if (h == NH - 2) { asm volatile("s_waitcnt vmcnt(0)" ::: "memory"); }
        if (h < NH - 1) __builtin_amdgcn_s_barrier();
    }
#undef STM

    #pragma unroll
    for (int mi = 0; mi < 8; ++mi) {
        int mrow = m0 + wm * 128 + mi * 16 + r16;
        #pragma unroll
        for (int nf = 0; nf < 4; ++nf) {
            int nb = wn * 64 + nf * 16 + kq * 4;
            float4 bb = *(const float4*)&b1[nb];
            float v0 = eluf(acc[mi][nf][0] + bb.x);
            float v1 = eluf(acc[mi][nf][1] + bb.y);
            float v2 = eluf(acc[mi][nf][2] + bb.z);
            float v3 = eluf(acc[mi][nf][3] + bb.w);
            ushort4 o; o.x = f2b(v0); o.y = f2b(v1); o.z = f2b(v2); o.w = f2b(v3);
            *(ushort4*)&C[(size_t)mrow * 256 + nb] = o;
        }
    }
}

// ===========================================================================
// weights f32 -> bf16 (packed):
// ef_w2 | m4_w1 | m4_w2 | f_wih | r_wih | e_w1 | m3_w1 | m3_w2
// ===========================================================================
__global__ __launch_bounds__(256) void wconv_k(
    const float* __restrict__ ef_w2, const float* __restrict__ m4_w1,
    const float* __restrict__ m4_w2, const float* __restrict__ f_wih,
    const float* __restrict__ r_wih, const float* __restrict__ e_w1,
    const float* __restrict__ m3_w1, const float* __restrict__ m3_w2,
    ushort_t* __restrict__ Wb)
{
    int i = blockIdx.x * 256 + threadIdx.x;   // < 622592
    const float* src; int off;
    if (i < 65536)       { src = ef_w2; off = i; }
    else if (i < 262144) { src = m4_w1; off = i - 65536; }
    else if (i < 327680) { src = m4_w2; off = i - 262144; }
    else if (i < 393216) { src = f_wih; off = i - 327680; }
    else if (i < 458752) { src = r_wih; off = i - 393216; }
    else if (i < 491520) { src = e_w1;  off = i - 458752; }
    else if (i < 557056) { src = m3_w1; off = i - 491520; }
    else                 { src = m3_w2; off = i - 557056; }
    Wb[i] = f2b(src[off]);
}

// ---------------------------------------------------------------------------
// edge2node: X[b,v,t,h] = (1/15)*sum_{e:RECV==v} EA[b,e,t,h] + rel@res_w.T + res_b
// Output bf16 (feeds MFMA mlp3).
// ---------------------------------------------------------------------------
__global__ __launch_bounds__(256) void e2n_k(
    const ushort_t* __restrict__ EA, const float* __restrict__ rel,
    const float* __restrict__ res_w, const float* __restrict__ res_b,
    ushort_t* __restrict__ X)
{
    const int idx = blockIdx.x;            // (b*V+v)*T + t
    const int t = idx & (T_ - 1);
    const int bv = idx >> 6;
    const int v = bv & (V_ - 1);
    const int b = bv >> 4;
    const int h = threadIdx.x;
    float sum = 0.f;
    #pragma unroll
    for (int i = 0; i < V_; ++i) {
        if (i == v) continue;
        int jj = (v < i) ? v : v - 1;
        int e = i * (V_ - 1) + jj;
        sum += b2f(EA[(((size_t)(b * E_ + e)) * T_ + t) * H_ + h]);
    }
    const float* rp = rel + ((size_t)bv * T_ + t) * DIN_;
    float res = res_b[h];
    #pragma unroll
    for (int d = 0; d < DIN_; ++d) res += rp[d] * res_w[h * DIN_ + d];
    X[((size_t)bv * T_ + t) * H_ + h] = f2b(sum * (1.f / 15.f) + res);
}

// ===========================================================================
// MFMA LSTM scan, both directions in one dispatch (blockIdx.y = dir).
// ===========================================================================
__global__ __launch_bounds__(256) void lstm_mfma4_k(
    const ushort_t* __restrict__ Gf, const ushort_t* __restrict__ Gr,
    const float* __restrict__ whh_f, const float* __restrict__ whh_r,
    ushort_t* __restrict__ COMB)
{
    __shared__ ushort_t hlds[2][1024];   // 2 x 2KB: h[seq][j] bf16, XOR-swizzled
    const int dir = blockIdx.y;
    const ushort_t* G = dir ? Gr : Gf;
    const float* whh = dir ? whh_r : whh_f;
    const int tid = threadIdx.x;
    const int lane = tid & 63;
    const int w = tid >> 6;              // wave id = j-block
    const int seq = lane & 15, kq = lane >> 4;
    const int be0 = blockIdx.x * 16;
    const int swz = (seq & 7) << 4;

    bf16x8 wf[4][2];
    #pragma unroll
    for (int a = 0; a < 4; ++a) {
        #pragma unroll
        for (int ks = 0; ks < 2; ++ks) {
            const float* p = whh + (size_t)((a * 4 + w) * 16 + seq) * 64 + ks * 32 + kq * 8;
            float4 x0 = *(const float4*)p;
            float4 x1 = *(const float4*)(p + 4);
            bf16x8 v;
            v[0] = (short)f2b(x0.x); v[1] = (short)f2b(x0.y);
            v[2] = (short)f2b(x0.z); v[3] = (short)f2b(x0.w);
            v[4] = (short)f2b(x1.x); v[5] = (short)f2b(x1.y);
            v[6] = (short)f2b(x1.z); v[7] = (short)f2b(x1.w);
            wf[a][ks] = v;
        }
    }

    const ushort_t* grow = G + ((size_t)(be0 + seq) * T_) * 256 + kq * 4;
    ushort_t* crow = COMB + ((size_t)(be0 + seq) * T_) * 128 + (dir ? 64 : 0) + 16 * w + 4 * kq;

    float c[4] = {};
    ushort4 gx[4];
    const int t0 = dir ? (T_ - 1) : 0;
    #pragma unroll
    for (int a = 0; a < 4; ++a)
        gx[a] = *(const ushort4*)(grow + (size_t)t0 * 256 + (a * 4 + w) * 16);

    for (int s = 0; s < T_; ++s) {
        const int t = dir ? (T_ - 1 - s) : s;
        f32x4 acc[4];
        #pragma unroll
        for (int a = 0; a < 4; ++a) {
            ushort4 g = gx[a];
            acc[a] = (f32x4){b2f(g.x), b2f(g.y), b2f(g.z), b2f(g.w)};
        }
        if (s < T_ - 1) {
            const int tn = dir ? (T_ - 2 - s) : (s + 1);
            #pragma unroll
            for (int a = 0; a < 4; ++a)
                gx[a] = *(const ushort4*)(grow + (size_t)tn * 256 + (a * 4 + w) * 16);
        }
        if (s) {
            bf16x8 af[2];
            #pragma unroll
            for (int ks = 0; ks < 2; ++ks) {
                int boff = (seq * 128 + ks * 64 + kq * 16) ^ swz;
                af[ks] = *(const bf16x8*)((const char*)hlds[(s - 1) & 1] + boff);
            }
            #pragma unroll
            for (int a = 0; a < 4; ++a) {
                acc[a] = __builtin_amdgcn_mfma_f32_16x16x32_bf16(wf[a][0], af[0], acc[a], 0, 0, 0);
                acc[a] = __builtin_amdgcn_mfma_f32_16x16x32_bf16(wf[a][1], af[1], acc[a], 0, 0, 0);
            }
        }
        float hh[4];
        #pragma unroll
        for (int r = 0; r < 4; ++r) {
            float zi = acc[0][r], zf = acc[1][r], zg = acc[2][r], zo = acc[3][r];
            float cc = fsig(zf) * c[r] + fsig(zi) * ftanh_(zg);
            c[r] = cc;
            hh[r] = fsig(zo) * ftanh_(cc);
        }
        ushort4 hv;
        hv.x = f2b(hh[0]); hv.y = f2b(hh[1]); hv.z = f2b(hh[2]); hv.w = f2b(hh[3]);
        int wb = (seq * 128 + 32 * w + 8 * kq) ^ swz;
        *(ushort4*)((char*)hlds[s & 1] + wb) = hv;
        *(ushort4*)(crow + (size_t)t * 128) = hv;
        asm volatile("s_waitcnt lgkmcnt(0)" ::: "memory");
        __builtin_amdgcn_sched_barrier(0);
        __builtin_amdgcn_s_barrier();
    }
}

// ---------------------------------------------------------------------------
// prior head: reads fwd hidden from comb[:, 0:64] (row stride 128)
// ---------------------------------------------------------------------------
__global__ __launch_bounds__(256) void prior_k(
    const ushort_t* __restrict__ COMB, const float* __restrict__ p_w,
    const float* __restrict__ p_b, float* __restrict__ out)
{
    const int row = blockIdx.x * 4 + (threadIdx.x >> 6);  // [0, BET)
    const int lane = threadIdx.x & 63;
    float hf = b2f(COMB[(size_t)row * 128 + lane]);
    float v0 = hf * p_w[lane];
    float v1 = hf * p_w[64 + lane];
    #pragma unroll
    for (int off = 32; off > 0; off >>= 1) {
        v0 += __shfl_down(v0, off, 64);
        v1 += __shfl_down(v1, off, 64);
    }
    if (lane == 0) {
        int t = row & (T_ - 1);
        int be = row >> 6;
        int e = be % E_, b = be / E_;
        size_t o = (((size_t)b * T_ + t) * E_ + e) * K_;
        out[o] = v0 + p_b[0];
        out[o + 1] = v1 + p_b[1];
    }
}

// ===========================================================================
// FUSED: ENCH = elu(COMB@e_w1.T + e_b1) in regs, then out = ENCH@e_w2.T + e_b2
// ===========================================================================
__global__ __launch_bounds__(512) void fused_enc_k(
    const ushort_t* __restrict__ COMB, const ushort_t* __restrict__ w_e1,
    const float* __restrict__ e_b1, const float* __restrict__ e_w2,
    const float* __restrict__ e_b2, float* __restrict__ out)
{
    __shared__ ushort_t sA[2][8][512];    // 16 KB
    __shared__ ushort_t sW[2][16][512];   // 32 KB
    __shared__ float part[128][4][2];     // 4 KB
    const int tid = threadIdx.x;
    const int lane = tid & 63;
    const int w = tid >> 6;
    const int wr = w >> 2, wc = w & 3;
    const int m0 = blockIdx.x * 128;
    const int r16 = lane & 15, kq = lane >> 4;

    const ushort_t* Asrc = COMB + (size_t)(m0 + w * 16 + r16) * 128 + kq * 8;
    const size_t woffA = (size_t)((2 * w) * 16 + r16) * 128 + kq * 8;
    const size_t woffB = (size_t)((2 * w + 1) * 16 + r16) * 128 + kq * 8;

    float4 w2v[2][4];
    #pragma unroll
    for (int j = 0; j < 2; ++j)
        #pragma unroll
        for (int nf = 0; nf < 4; ++nf)
            w2v[j][nf] = *(const float4*)&e_w2[j * 256 + wc * 64 + nf * 16 + kq * 4];

    f32x4 acc[4][4];
    #pragma unroll
    for (int i = 0; i < 4; ++i)
        #pragma unroll
        for (int j = 0; j < 4; ++j)
            acc[i][j] = (f32x4){0.f, 0.f, 0.f, 0.f};

#define FE_STAGE(bufi, kt_) do {                                             \
    gll16(Asrc + (kt_) * 32, &sA[bufi][w][0]);                               \
    gll16(w_e1 + woffA + (kt_) * 32, &sW[bufi][2 * w][0]);                   \
    gll16(w_e1 + woffB + (kt_) * 32, &sW[bufi][2 * w + 1][0]);               \
} while (0)

    FE_STAGE(0, 0);
    asm volatile("s_waitcnt vmcnt(0)" ::: "memory");
    __builtin_amdgcn_s_barrier();

    for (int s = 0; s < 4; ++s) {
        const int buf = s & 1;
        if (s < 3) FE_STAGE(buf ^ 1, s + 1);
        bf16x8 af[4], bfr[4];
        #pragma unroll
        for (int mf = 0; mf < 4; ++mf)
            af[mf] = *(const bf16x8*)&sA[buf][wr * 4 + mf][lane * 8];
        #pragma unroll
        for (int nf = 0; nf < 4; ++nf)
            bfr[nf] = *(const bf16x8*)&sW[buf][wc * 4 + nf][lane * 8];
        #pragma unroll
        for (int mf = 0; mf < 4; ++mf)
            #pragma unroll
            for (int nf = 0; nf < 4; ++nf)
                acc[mf][nf] = __builtin_amdgcn_mfma_f32_16x16x32_bf16(bfr[nf], af[mf], acc[mf][nf], 0, 0, 0);
        asm volatile("s_waitcnt vmcnt(0)" ::: "memory");
        __builtin_amdgcn_s_barrier();
    }

    #pragma unroll
    for (int mf = 0; mf < 4; ++mf) {
        float s0 = 0.f, s1 = 0.f;
        #pragma unroll
        for (int nf = 0; nf < 4; ++nf) {
            int col = wc * 64 + nf * 16 + kq * 4;
            float4 bb = *(const float4*)&e_b1[col];
            float v0 = eluf(acc[mf][nf][0] + bb.x);
            float v1 = eluf(acc[mf][nf][1] + bb.y);
            float v2 = eluf(acc[mf][nf][2] + bb.z);
            float v3 = eluf(acc[mf][nf][3] + bb.w);
            s0 += v0 * w2v[0][nf].x + v1 * w2v[0][nf].y + v2 * w2v[0][nf].z + v3 * w2v[0][nf].w;
            s1 += v0 * w2v[1][nf].x + v1 * w2v[1][nf].y + v2 * w2v[1][nf].z + v3 * w2v[1][nf].w;
        }
        s0 += __shfl_xor(s0, 16, 64); s0 += __shfl_xor(s0, 32, 64);
        s1 += __shfl_xor(s1, 16, 64); s1 += __shfl_xor(s1, 32, 64);
        if (kq == 0) {
            part[wr * 64 + mf * 16 + r16][wc][0] = s0;
            part[wr * 64 + mf * 16 + r16][wc][1] = s1;
        }
    }
    __syncthreads();
    if (tid < 256) {
        int row = tid >> 1, k = tid & 1;
        float v = part[row][0][k] + part[row][1][k] + part[row][2][k] + part[row][3][k] + e_b2[k];
        int gr = m0 + row;
        int be = gr >> 6, t = gr & 63;
        int e = be % E_, b = be / E_;
        out[(size_t)(B_ * T_ * E_ * K_) + (((size_t)b * T_ + t) * E_ + e) * K_ + k] = v;
    }
#undef FE_STAGE
}

// ---------------------------------------------------------------------------
extern "C" void kernel_launch(void* const* d_in, const int* in_sizes, int n_in,
                              void* d_out, int out_size, void* d_ws, size_t ws_size,
                              hipStream_t stream)
{
    const float* rel    = (const float*)d_in[0];
    const float* ear    = (const float*)d_in[1];
    const float* epos   = (const float*)d_in[2];
    const float* ef_w1  = (const float*)d_in[3];
    const float* ef_b1  = (const float*)d_in[4];
    const float* ef_w2  = (const float*)d_in[5];
    const float* ef_b2  = (const float*)d_in[6];
    const float* res_w  = (const float*)d_in[7];
    const float* res_b  = (const float*)d_in[8];
    const float* m3_w1  = (const float*)d_in[9];
    const float* m3_b1  = (const float*)d_in[10];
    const float* m3_w2  = (const float*)d_in[11];
    const float* m3_b2  = (const float*)d_in[12];
    const float* m4_w1  = (const float*)d_in[13];
    const float* m4_b1  = (const float*)d_in[14];
    const float* m4_w2  = (const float*)d_in[15];
    const float* m4_b2  = (const float*)d_in[16];
    const float* f_wih  = (const float*)d_in[17];
    const float* f_whh  = (const float*)d_in[18];
    const float* f_bih  = (const float*)d_in[19];
    const float* f_bhh  = (const float*)d_in[20];
    const float* r_wih  = (const float*)d_in[21];
    const float* r_whh  = (const float*)d_in[22];
    const float* r_bih  = (const float*)d_in[23];
    const float* r_bhh  = (const float*)d_in[24];
    const float* p_w    = (const float*)d_in[25];
    const float* p_b    = (const float*)d_in[26];
    const float* e_w1   = (const float*)d_in[27];
    const float* e_b1   = (const float*)d_in[28];
    const float* e_w2   = (const float*)d_in[29];
    const float* e_b2   = (const float*)d_in[30];
    float* out = (float*)d_out;

    // workspace layout (bytes), total ~163 MB
    char* ws = (char*)d_ws;
    const size_t BIGB  = (size_t)BET_ * H_ * sizeof(ushort_t);   // 62,914,560
    const size_t COMBB = (size_t)BET_ * 128 * sizeof(ushort_t);  // 31,457,280
    const size_t X2BB  = (size_t)BVT_ * H_ * sizeof(ushort_t);   //  4,194,304
    ushort_t* R1   = (ushort_t*)(ws);
    ushort_t* R2   = (ushort_t*)(ws + BIGB);
    ushort_t* COMB = (ushort_t*)(ws + 2 * BIGB);
    ushort_t* X2b  = (ushort_t*)(ws + 2 * BIGB + COMBB);
    ushort_t* Wb   = (ushort_t*)(ws + 2 * BIGB + COMBB + X2BB);
    // node-stage bf16 X lives inside (dead) R1 region
    ushort_t* Xbf = (ushort_t*)(ws);
    // packed bf16 weight offsets (elements)
    const ushort_t* wb_ef2  = Wb + 0;
    const ushort_t* wb_m41  = Wb + 65536;
    const ushort_t* wb_m42  = Wb + 262144;
    const ushort_t* wb_fwih = Wb + 327680;
    const ushort_t* wb_rwih = Wb + 393216;
    const ushort_t* wb_ew1  = Wb + 458752;
    const ushort_t* wb_m31  = Wb + 491520;
    const ushort_t* wb_m32  = Wb + 557056;

    dim3 blk(256);
    dim3 blk8(512);
    dim3 g128(BET_ / 128);     // 960 blocks (BM=128 kernels)
    dim3 g256(BET_ / 256);     // 480 blocks (BM=256 kernels)
    dim3 gE64(BET_ / 64, 4);   // VALU ein GEMM

    // 0. weights -> bf16 (incl. mlp3)
    wconv_k<<<2432, blk, 0, stream>>>(ef_w2, m4_w1, m4_w2, f_wih, r_wih, e_w1, m3_w1, m3_w2, Wb);
    // 1. edge-filter MLP: VALU ein (K=16) -> R1, then MFMA ef2 -> R2 (EA)
    gemm_ein_k<<<gE64, blk, 0, stream>>>(ear, epos, ef_w1, ef_b1, R1);
    gemm8_k<256, 1><<<g256, blk8, 0, stream>>>(R1, wb_ef2, ef_b2, nullptr, R2);
    // 2. edge2node + residual -> bf16 X (aliases R1; H1 dead)
    e2n_k<<<BVT_, blk, 0, stream>>>(R2, rel, res_w, res_b, Xbf);
    // 3. fused mlp3 (both layers, MFMA) -> X2b
    gemm8_mlp3_k<<<BVT_ / 128, blk8, 0, stream>>>(Xbf, wb_m31, m3_b1, wb_m32, m3_b2, X2b);
    // 4. node2edge gather + mlp4 layer 1 -> T1 (R1)
    gemm8_mlp4_k<<<g256, blk8, 0, stream>>>(X2b, R2, wb_m41, m4_b1, R1);
    // 5. m4l2 -> M2 (R2; EA dead), then merged gates: GF -> R1, GR -> R2 in-place
    gemm8_k<256, 1><<<g256, blk8, 0, stream>>>(R1, wb_m42, m4_b2, nullptr, R2);
    gemm8_gates_k<<<g128, blk8, 0, stream>>>(R2, wb_fwih, wb_rwih,
                                             f_bih, f_bhh, r_bih, r_bhh, R1, R2);
    // 6. LSTM scans, both directions in one dispatch (Gf=R1, Gr=R2)
    lstm_mfma4_k<<<dim3(BE_ / 16, 2), blk, 0, stream>>>(R1, R2, f_whh, r_whh, COMB);
    // 7. heads
    prior_k<<<BET_ / 4, blk, 0, stream>>>(COMB, p_w, p_b, out);
    fused_enc_k<<<g128, blk8, 0, stream>>>(COMB, wb_ew1, e_b1, e_w2, e_b2, out);
}